// Round 16
// baseline (335.179 us; speedup 1.0000x reference)
//
#include <hip/hip_runtime.h>
#include <math.h>

#define HH 64

// ---------------- init ----------------

__global__ void k_init(int* __restrict__ head, float* __restrict__ sums,
                       int* __restrict__ cursor, int n, int pn) {
    int i = blockIdx.x * blockDim.x + threadIdx.x;
    if (i < n) head[i] = -1;
    if (i < pn) sums[i] = 0.f;
    if (i == 0) *cursor = 0;
}

// ---------------- CSR build: pure linked-list pass (the atomic-scatter floor) ----------------
__global__ void k_link(const int* __restrict__ col, int E,
                       int* __restrict__ head, int* __restrict__ next) {
    int e = blockIdx.x * blockDim.x + threadIdx.x;
    if (e >= E) return;
    int c = col[e];
    int prev = atomicExch(&head[c], e);
    next[e] = prev;
}

// ---------------- walk + CSR alloc (R11-verified, standalone) ----------------
__global__ __launch_bounds__(256) void k_walk_alloc(const int* __restrict__ row,
                                                    const int* __restrict__ head,
                                                    const int* __restrict__ next,
                                                    int* __restrict__ cursor,
                                                    int* __restrict__ rowptr,
                                                    int* __restrict__ cnt,
                                                    float* __restrict__ dinv,
                                                    int* __restrict__ csr, int n) {
    int node = blockIdx.x * blockDim.x + threadIdx.x;
    int lane = threadIdx.x & 63;
    int len = 0;
    int h = -1;
    if (node < n) {
        h = head[node];
        for (int p = h; p >= 0; p = next[p]) ++len;
        dinv[node] = rsqrtf((float)(len + 1));
    }
    int incl = len;
#pragma unroll
    for (int off = 1; off < 64; off <<= 1) {
        int t = __shfl_up(incl, off, 64);
        if (lane >= off) incl += t;
    }
    int total = __shfl(incl, 63, 64);
    int base = 0;
    if (lane == 0 && total > 0) base = atomicAdd(cursor, total);
    base = __shfl(base, 0, 64);
    int dst = base + incl - len;
    if (node < n) {
        rowptr[node] = dst;
        cnt[node]    = len;
        for (int p = h; p >= 0; p = next[p]) csr[dst++] = row[p];
    }
}

// ---------------- dense transform: k-chunked register-tiled GEMM ----------------
// SCALE=true: output pre-scaled by dinv[node] (layers 2-3).
// SCALE=false: plain lin (layer 1; dinv applied per-edge in gather_w).
template<int FIN, bool SCALE>
__global__ __launch_bounds__(256, 4) void k_gemm2(const float* __restrict__ x,
                                                  const float* __restrict__ W,
                                                  const float* __restrict__ dinv,
                                                  float* __restrict__ linS, int n) {
    constexpr int KC = 32;
    constexpr int XS = 68;
    __shared__ __align__(16) float Ws[FIN][HH];
    __shared__ __align__(16) float xs_t[KC][XS];
    const int tid = threadIdx.x;
    const int tx = tid & 15;
    const int ty = tid >> 4;
    const int node0 = blockIdx.x * 64;

    for (int i = tid * 4; i < FIN * HH; i += 1024)
        *(float4*)&Ws[0][i] = *(const float4*)&W[i];

    float acc[4][4] = {};
    const int rr0 = tid >> 3;
    const int cc  = (tid & 7) * 4;

    for (int kc = 0; kc < FIN; kc += KC) {
        __syncthreads();
        for (int rr = rr0; rr < 64; rr += 32) {
            float4 v = make_float4(0.f, 0.f, 0.f, 0.f);
            if (node0 + rr < n) v = *(const float4*)&x[(size_t)(node0 + rr) * FIN + kc + cc];
            xs_t[cc + 0][rr] = v.x;
            xs_t[cc + 1][rr] = v.y;
            xs_t[cc + 2][rr] = v.z;
            xs_t[cc + 3][rr] = v.w;
        }
        __syncthreads();
#pragma unroll 4
        for (int k = 0; k < KC; ++k) {
            float4 a4 = *(const float4*)&xs_t[k][ty * 4];
            float4 b4 = *(const float4*)&Ws[kc + k][tx * 4];
            acc[0][0] = fmaf(a4.x, b4.x, acc[0][0]);
            acc[0][1] = fmaf(a4.x, b4.y, acc[0][1]);
            acc[0][2] = fmaf(a4.x, b4.z, acc[0][2]);
            acc[0][3] = fmaf(a4.x, b4.w, acc[0][3]);
            acc[1][0] = fmaf(a4.y, b4.x, acc[1][0]);
            acc[1][1] = fmaf(a4.y, b4.y, acc[1][1]);
            acc[1][2] = fmaf(a4.y, b4.z, acc[1][2]);
            acc[1][3] = fmaf(a4.y, b4.w, acc[1][3]);
            acc[2][0] = fmaf(a4.z, b4.x, acc[2][0]);
            acc[2][1] = fmaf(a4.z, b4.y, acc[2][1]);
            acc[2][2] = fmaf(a4.z, b4.z, acc[2][2]);
            acc[2][3] = fmaf(a4.z, b4.w, acc[2][3]);
            acc[3][0] = fmaf(a4.w, b4.x, acc[3][0]);
            acc[3][1] = fmaf(a4.w, b4.y, acc[3][1]);
            acc[3][2] = fmaf(a4.w, b4.z, acc[3][2]);
            acc[3][3] = fmaf(a4.w, b4.w, acc[3][3]);
        }
    }

#pragma unroll
    for (int i = 0; i < 4; ++i) {
        int node = node0 + ty * 4 + i;
        if (node < n) {
            float d = SCALE ? dinv[node] : 1.f;
            float4 o = make_float4(acc[i][0] * d, acc[i][1] * d, acc[i][2] * d, acc[i][3] * d);
            *(float4*)&linS[(size_t)node * HH + tx * 4] = o;
        }
    }
}

// ---------------- layer-1 gather: lin unscaled, weight = dinv[src] per edge ----------------
// 8-deep unroll (extended from R12-verified 4-deep).
__global__ void k_gather_w(const float* __restrict__ lin, const int* __restrict__ csr,
                           const int* __restrict__ rowptr, const int* __restrict__ cnt,
                           const float* __restrict__ dinv, const float* __restrict__ b,
                           float* __restrict__ hout, int n) {
    int node = blockIdx.x * (blockDim.x >> 6) + (threadIdx.x >> 6);
    int lane = threadIdx.x & 63;
    if (node >= n) return;
    int start = rowptr[node];
    int end = start + cnt[node];
    float di = dinv[node];
    float acc0 = di * lin[(size_t)node * HH + lane];   // self: dinv[c]*lin[c]
    float acc1 = 0.f, acc2 = 0.f, acc3 = 0.f;
    for (int base = start; base < end; base += 64) {
        int m = end - base; if (m > 64) m = 64;
        int   sv = (base + lane < end) ? csr[base + lane] : 0;
        float wv = (base + lane < end) ? dinv[sv] : 0.f;
        int j = 0;
        for (; j + 7 < m; j += 8) {
            int s0 = __shfl(sv, j, 64);     float w0 = __shfl(wv, j, 64);
            int s1 = __shfl(sv, j + 1, 64); float w1 = __shfl(wv, j + 1, 64);
            int s2 = __shfl(sv, j + 2, 64); float w2 = __shfl(wv, j + 2, 64);
            int s3 = __shfl(sv, j + 3, 64); float w3 = __shfl(wv, j + 3, 64);
            int s4 = __shfl(sv, j + 4, 64); float w4 = __shfl(wv, j + 4, 64);
            int s5 = __shfl(sv, j + 5, 64); float w5 = __shfl(wv, j + 5, 64);
            int s6 = __shfl(sv, j + 6, 64); float w6 = __shfl(wv, j + 6, 64);
            int s7 = __shfl(sv, j + 7, 64); float w7 = __shfl(wv, j + 7, 64);
            float v0 = lin[(size_t)s0 * HH + lane];
            float v1 = lin[(size_t)s1 * HH + lane];
            float v2 = lin[(size_t)s2 * HH + lane];
            float v3 = lin[(size_t)s3 * HH + lane];
            float v4 = lin[(size_t)s4 * HH + lane];
            float v5 = lin[(size_t)s5 * HH + lane];
            float v6 = lin[(size_t)s6 * HH + lane];
            float v7 = lin[(size_t)s7 * HH + lane];
            acc0 = fmaf(w0, v0, acc0);
            acc1 = fmaf(w1, v1, acc1);
            acc2 = fmaf(w2, v2, acc2);
            acc3 = fmaf(w3, v3, acc3);
            acc0 = fmaf(w4, v4, acc0);
            acc1 = fmaf(w5, v5, acc1);
            acc2 = fmaf(w6, v6, acc2);
            acc3 = fmaf(w7, v7, acc3);
        }
        for (; j < m; ++j) {
            int s0 = __shfl(sv, j, 64); float w0 = __shfl(wv, j, 64);
            acc0 = fmaf(w0, lin[(size_t)s0 * HH + lane], acc0);
        }
    }
    float v = di * ((acc0 + acc1) + (acc2 + acc3)) + b[lane];
    float ss = v * v;
#pragma unroll
    for (int off = 1; off < 64; off <<= 1) ss += __shfl_xor(ss, off, 64);
    v = v / fmaxf(sqrtf(ss), 1e-12f);
    hout[(size_t)node * HH + lane] = fmaxf(v, 0.f);
}

// ---------------- layers 2-3 gather: linS pre-scaled, 16-deep unroll ----------------
__global__ void k_gather(const float* __restrict__ linS, const int* __restrict__ csr,
                         const int* __restrict__ rowptr, const int* __restrict__ cnt,
                         const float* __restrict__ dinv, const float* __restrict__ b,
                         float* __restrict__ hout, int n) {
    int node = blockIdx.x * (blockDim.x >> 6) + (threadIdx.x >> 6);
    int lane = threadIdx.x & 63;
    if (node >= n) return;
    int start = rowptr[node];
    int end = start + cnt[node];
    float di = dinv[node];
    float acc0 = linS[(size_t)node * HH + lane];   // self term (carries one dinv[c])
    float acc1 = 0.f, acc2 = 0.f, acc3 = 0.f;
    for (int base = start; base < end; base += 64) {
        int m = end - base; if (m > 64) m = 64;
        int sv = (base + lane < end) ? csr[base + lane] : 0;
        int j = 0;
        for (; j + 15 < m; j += 16) {
            int s0 = __shfl(sv, j, 64);      int s1 = __shfl(sv, j + 1, 64);
            int s2 = __shfl(sv, j + 2, 64);  int s3 = __shfl(sv, j + 3, 64);
            int s4 = __shfl(sv, j + 4, 64);  int s5 = __shfl(sv, j + 5, 64);
            int s6 = __shfl(sv, j + 6, 64);  int s7 = __shfl(sv, j + 7, 64);
            int s8 = __shfl(sv, j + 8, 64);  int s9 = __shfl(sv, j + 9, 64);
            int sa = __shfl(sv, j + 10, 64); int sb = __shfl(sv, j + 11, 64);
            int sc = __shfl(sv, j + 12, 64); int sd = __shfl(sv, j + 13, 64);
            int se = __shfl(sv, j + 14, 64); int sf = __shfl(sv, j + 15, 64);
            float v0 = linS[(size_t)s0 * HH + lane];
            float v1 = linS[(size_t)s1 * HH + lane];
            float v2 = linS[(size_t)s2 * HH + lane];
            float v3 = linS[(size_t)s3 * HH + lane];
            float v4 = linS[(size_t)s4 * HH + lane];
            float v5 = linS[(size_t)s5 * HH + lane];
            float v6 = linS[(size_t)s6 * HH + lane];
            float v7 = linS[(size_t)s7 * HH + lane];
            float v8 = linS[(size_t)s8 * HH + lane];
            float v9 = linS[(size_t)s9 * HH + lane];
            float va = linS[(size_t)sa * HH + lane];
            float vb = linS[(size_t)sb * HH + lane];
            float vc = linS[(size_t)sc * HH + lane];
            float vd = linS[(size_t)sd * HH + lane];
            float ve = linS[(size_t)se * HH + lane];
            float vf = linS[(size_t)sf * HH + lane];
            acc0 += v0; acc1 += v1; acc2 += v2; acc3 += v3;
            acc0 += v4; acc1 += v5; acc2 += v6; acc3 += v7;
            acc0 += v8; acc1 += v9; acc2 += va; acc3 += vb;
            acc0 += vc; acc1 += vd; acc2 += ve; acc3 += vf;
        }
        for (; j + 7 < m; j += 8) {
            int s0 = __shfl(sv, j, 64);     int s1 = __shfl(sv, j + 1, 64);
            int s2 = __shfl(sv, j + 2, 64); int s3 = __shfl(sv, j + 3, 64);
            int s4 = __shfl(sv, j + 4, 64); int s5 = __shfl(sv, j + 5, 64);
            int s6 = __shfl(sv, j + 6, 64); int s7 = __shfl(sv, j + 7, 64);
            float v0 = linS[(size_t)s0 * HH + lane];
            float v1 = linS[(size_t)s1 * HH + lane];
            float v2 = linS[(size_t)s2 * HH + lane];
            float v3 = linS[(size_t)s3 * HH + lane];
            float v4 = linS[(size_t)s4 * HH + lane];
            float v5 = linS[(size_t)s5 * HH + lane];
            float v6 = linS[(size_t)s6 * HH + lane];
            float v7 = linS[(size_t)s7 * HH + lane];
            acc0 += v0; acc1 += v1; acc2 += v2; acc3 += v3;
            acc0 += v4; acc1 += v5; acc2 += v6; acc3 += v7;
        }
        for (; j < m; ++j) {
            int s0 = __shfl(sv, j, 64);
            acc0 += linS[(size_t)s0 * HH + lane];
        }
    }
    float v = di * ((acc0 + acc1) + (acc2 + acc3)) + b[lane];
    float ss = v * v;
#pragma unroll
    for (int off = 1; off < 64; off <<= 1) ss += __shfl_xor(ss, off, 64);
    v = v / fmaxf(sqrtf(ss), 1e-12f);
    hout[(size_t)node * HH + lane] = fmaxf(v, 0.f);
}

// ---------------- pooling ----------------
__global__ __launch_bounds__(256) void k_pool(const float* __restrict__ node_emb,
                                              const int* __restrict__ batch,
                                              float* __restrict__ sums,
                                              float* __restrict__ cnts, int n) {
    const int NPW = 16;
    int wave = blockIdx.x * 4 + (threadIdx.x >> 6);
    int lane = threadIdx.x & 63;
    int start = wave * NPW;
    if (start >= n) return;
    int end = start + NPW; if (end > n) end = n;
    int cur = batch[start];
    float acc = 0.f;
    int runlen = 0;
    for (int node = start; node < end; ++node) {
        int g = batch[node];
        if (g != cur) {
            atomicAdd(&sums[(size_t)cur * HH + lane], acc);
            if (lane == 0) atomicAdd(&cnts[cur], (float)runlen);
            acc = 0.f; runlen = 0; cur = g;
        }
        acc += node_emb[(size_t)node * HH + lane];
        ++runlen;
    }
    atomicAdd(&sums[(size_t)cur * HH + lane], acc);
    if (lane == 0) atomicAdd(&cnts[cur], (float)runlen);
}

// ---------------- classifier + softmax ----------------
__global__ void k_final2(const float* __restrict__ sums, const float* __restrict__ cnts,
                         const float* __restrict__ Wm, const float* __restrict__ bm,
                         float* __restrict__ logits, float* __restrict__ probs,
                         float* __restrict__ graph_emb) {
    int g = blockIdx.x;
    int lane = threadIdx.x;
    float mean = sums[(size_t)g * HH + lane] / fmaxf(cnts[g], 1.0f);
    graph_emb[(size_t)g * HH + lane] = mean;

    __shared__ float semb[HH];
    __shared__ float slog[16];
    semb[lane] = mean;
    __syncthreads();
    if (lane < 10) {
        float acc = bm[lane];
        for (int k = 0; k < HH; ++k) acc = fmaf(semb[k], Wm[k * 10 + lane], acc);
        slog[lane] = acc;
    }
    __syncthreads();
    if (lane < 10) {
        float mx = -1e30f;
        for (int j = 0; j < 10; ++j) mx = fmaxf(mx, slog[j]);
        float den = 0.f;
        for (int j = 0; j < 10; ++j) den += __expf(slog[j] - mx);
        float lg = slog[lane];
        logits[g * 10 + lane] = lg;
        probs[g * 10 + lane] = __expf(lg - mx) / den;
    }
}

// ---------------- launch ----------------

extern "C" void kernel_launch(void* const* d_in, const int* in_sizes, int n_in,
                              void* d_out, int out_size, void* d_ws, size_t ws_size,
                              hipStream_t stream) {
    const float* x     = (const float*)d_in[0];
    const int*   ei    = (const int*)  d_in[1];
    const int*   batch = (const int*)  d_in[2];
    const float* W1 = (const float*)d_in[3];  const float* b1 = (const float*)d_in[4];
    const float* W2 = (const float*)d_in[5];  const float* b2 = (const float*)d_in[6];
    const float* W3 = (const float*)d_in[7];  const float* b3 = (const float*)d_in[8];
    const float* Wm = (const float*)d_in[9];  const float* bm = (const float*)d_in[10];

    const int N = in_sizes[2];
    const int E = in_sizes[1] / 2;
    const int G = (out_size - N * HH) / (2 * 10 + HH);

    const int* row = ei;
    const int* col = ei + E;

    float* out       = (float*)d_out;
    float* logits    = out;
    float* probs     = out + (size_t)G * 10;
    float* node_emb  = out + (size_t)2 * G * 10;
    float* graph_emb = node_emb + (size_t)N * HH;

    char* w = (char*)d_ws;
    auto alloc = [&](size_t bytes) { char* p = w; w += (bytes + 255) & ~(size_t)255; return p; };
    float* dinv    = (float*)alloc((size_t)N * 4);
    int*   cnt     = (int*)  alloc((size_t)N * 4);
    int*   rowptr  = (int*)  alloc((size_t)N * 4);
    int*   head    = (int*)  alloc((size_t)N * 4);
    int*   nxt     = (int*)  alloc((size_t)E * 4);
    int*   cursor  = (int*)  alloc(256);
    float* sums    = (float*)alloc((size_t)G * HH * 4 + (size_t)G * 4);
    float* cnts    = sums + (size_t)G * HH;
    int*   csr     = (int*)  alloc((size_t)E * 4);
    float* bufA    = (float*)alloc((size_t)N * HH * 4);
    float* bufB    = (float*)alloc((size_t)N * HH * 4);

    const int B = 256;
    dim3 blk(B);
    int node_blocks = (N + 3) / 4;
    int gemm_blocks = (N + 63) / 64;
    int nB = (N + B - 1) / B;
    int eB = (E + B - 1) / B;
    int poolN = G * HH + G;
    int pool_blocks = (N + 63) / 64;

    // CSR build: init -> pure link -> walk/alloc (separate; R12 fusion lesson:
    // wave-serial fusion with the GEMM throttles both phases)
    k_init<<<nB, blk, 0, stream>>>(head, sums, cursor, N, poolN);
    k_link<<<eB, blk, 0, stream>>>(col, E, head, nxt);
    k_walk_alloc<<<nB, blk, 0, stream>>>(row, head, nxt, cursor, rowptr, cnt, dinv, csr, N);

    // layer 1: unscaled gemm + weighted gather (bufA -> bufB = h1)
    k_gemm2<128, false><<<gemm_blocks, blk, 0, stream>>>(x, W1, dinv, bufA, N);
    k_gather_w<<<node_blocks, blk, 0, stream>>>(bufA, csr, rowptr, cnt, dinv, b1, bufB, N);
    // layer 2: prescaled gemm + gather (bufB -> bufA -> bufB = h2)
    k_gemm2<64, true><<<gemm_blocks, blk, 0, stream>>>(bufB, W2, dinv, bufA, N);
    k_gather<<<node_blocks, blk, 0, stream>>>(bufA, csr, rowptr, cnt, dinv, b2, bufB, N);
    // layer 3: prescaled gemm + gather (bufB -> bufA -> node_emb)
    k_gemm2<64, true><<<gemm_blocks, blk, 0, stream>>>(bufB, W3, dinv, bufA, N);
    k_gather<<<node_blocks, blk, 0, stream>>>(bufA, csr, rowptr, cnt, dinv, b3, node_emb, N);

    // pool + classifier
    k_pool<<<pool_blocks, blk, 0, stream>>>(node_emb, batch, sums, cnts, N);
    k_final2<<<G, dim3(64), 0, stream>>>(sums, cnts, Wm, bm, logits, probs, graph_emb);
}

// Round 17
// 311.065 us; speedup vs baseline: 1.0775x; 1.0775x over previous
//
#include <hip/hip_runtime.h>
#include <math.h>

#define HH 64

// ---------------- init ----------------

__global__ void k_init(int* __restrict__ head, float* __restrict__ sums,
                       int* __restrict__ cursor, int n, int pn) {
    int i = blockIdx.x * blockDim.x + threadIdx.x;
    if (i < n) head[i] = -1;
    if (i < pn) sums[i] = 0.f;
    if (i == 0) *cursor = 0;
}

// ---------------- CSR build: pure linked-list pass ----------------
__global__ void k_link(const int* __restrict__ col, int E,
                       int* __restrict__ head, int* __restrict__ next) {
    int e = blockIdx.x * blockDim.x + threadIdx.x;
    if (e >= E) return;
    int c = col[e];
    int prev = atomicExch(&head[c], e);
    next[e] = prev;
}

// ---------------- fused: list-walk/CSR-alloc + layer-1 GEMM (R15-verified, best) ----------------
template<int FIN>
__global__ __launch_bounds__(256, 3) void k_walk_gemm(const int* __restrict__ row,
                                                      const int* __restrict__ head,
                                                      const int* __restrict__ next,
                                                      int* __restrict__ cursor,
                                                      int* __restrict__ rowptr,
                                                      int* __restrict__ cnt,
                                                      float* __restrict__ dinv,
                                                      int* __restrict__ csr,
                                                      const float* __restrict__ x,
                                                      const float* __restrict__ W,
                                                      float* __restrict__ lin, int n) {
    constexpr int KC = 32;
    constexpr int XS = 68;
    __shared__ __align__(16) float Ws[FIN][HH];
    __shared__ __align__(16) float xs_t[KC][XS];
    const int tid = threadIdx.x;

    // ---- walk + alloc ----
    {
        int node = blockIdx.x * 256 + tid;
        int lane = tid & 63;
        if (node - tid < n) {
            int len = 0, h = -1;
            if (node < n) {
                h = head[node];
                for (int p = h; p >= 0; p = next[p]) ++len;
                dinv[node] = rsqrtf((float)(len + 1));
            }
            int incl = len;
#pragma unroll
            for (int off = 1; off < 64; off <<= 1) {
                int t = __shfl_up(incl, off, 64);
                if (lane >= off) incl += t;
            }
            int total = __shfl(incl, 63, 64);
            int base = 0;
            if (lane == 0 && total > 0) base = atomicAdd(cursor, total);
            base = __shfl(base, 0, 64);
            int dst = base + incl - len;
            if (node < n) {
                rowptr[node] = dst;
                cnt[node]    = len;
                for (int p = h; p >= 0; p = next[p]) csr[dst++] = row[p];
            }
        }
    }

    // ---- layer-1 gemm (unscaled output) ----
    const int tx = tid & 15;
    const int ty = tid >> 4;
    const int node0 = blockIdx.x * 64;
    if (node0 >= n) return;

    for (int i = tid * 4; i < FIN * HH; i += 1024)
        *(float4*)&Ws[0][i] = *(const float4*)&W[i];

    float acc[4][4] = {};
    const int rr0 = tid >> 3;
    const int cc  = (tid & 7) * 4;

    for (int kc = 0; kc < FIN; kc += KC) {
        __syncthreads();
        for (int rr = rr0; rr < 64; rr += 32) {
            float4 v = make_float4(0.f, 0.f, 0.f, 0.f);
            if (node0 + rr < n) v = *(const float4*)&x[(size_t)(node0 + rr) * FIN + kc + cc];
            xs_t[cc + 0][rr] = v.x;
            xs_t[cc + 1][rr] = v.y;
            xs_t[cc + 2][rr] = v.z;
            xs_t[cc + 3][rr] = v.w;
        }
        __syncthreads();
#pragma unroll 4
        for (int k = 0; k < KC; ++k) {
            float4 a4 = *(const float4*)&xs_t[k][ty * 4];
            float4 b4 = *(const float4*)&Ws[kc + k][tx * 4];
            acc[0][0] = fmaf(a4.x, b4.x, acc[0][0]);
            acc[0][1] = fmaf(a4.x, b4.y, acc[0][1]);
            acc[0][2] = fmaf(a4.x, b4.z, acc[0][2]);
            acc[0][3] = fmaf(a4.x, b4.w, acc[0][3]);
            acc[1][0] = fmaf(a4.y, b4.x, acc[1][0]);
            acc[1][1] = fmaf(a4.y, b4.y, acc[1][1]);
            acc[1][2] = fmaf(a4.y, b4.z, acc[1][2]);
            acc[1][3] = fmaf(a4.y, b4.w, acc[1][3]);
            acc[2][0] = fmaf(a4.z, b4.x, acc[2][0]);
            acc[2][1] = fmaf(a4.z, b4.y, acc[2][1]);
            acc[2][2] = fmaf(a4.z, b4.z, acc[2][2]);
            acc[2][3] = fmaf(a4.z, b4.w, acc[2][3]);
            acc[3][0] = fmaf(a4.w, b4.x, acc[3][0]);
            acc[3][1] = fmaf(a4.w, b4.y, acc[3][1]);
            acc[3][2] = fmaf(a4.w, b4.z, acc[3][2]);
            acc[3][3] = fmaf(a4.w, b4.w, acc[3][3]);
        }
    }

#pragma unroll
    for (int i = 0; i < 4; ++i) {
        int node = node0 + ty * 4 + i;
        if (node < n) *(float4*)&lin[(size_t)node * HH + tx * 4] = *(float4*)acc[i];
    }
}

// ---------------- dense transform (layers 2-3): pre-scaled by dinv ----------------
template<int FIN>
__global__ __launch_bounds__(256, 4) void k_gemm2(const float* __restrict__ x,
                                                  const float* __restrict__ W,
                                                  const float* __restrict__ dinv,
                                                  float* __restrict__ linS, int n) {
    constexpr int KC = 32;
    constexpr int XS = 68;
    __shared__ __align__(16) float Ws[FIN][HH];
    __shared__ __align__(16) float xs_t[KC][XS];
    const int tid = threadIdx.x;
    const int tx = tid & 15;
    const int ty = tid >> 4;
    const int node0 = blockIdx.x * 64;

    for (int i = tid * 4; i < FIN * HH; i += 1024)
        *(float4*)&Ws[0][i] = *(const float4*)&W[i];

    float acc[4][4] = {};
    const int rr0 = tid >> 3;
    const int cc  = (tid & 7) * 4;

    for (int kc = 0; kc < FIN; kc += KC) {
        __syncthreads();
        for (int rr = rr0; rr < 64; rr += 32) {
            float4 v = make_float4(0.f, 0.f, 0.f, 0.f);
            if (node0 + rr < n) v = *(const float4*)&x[(size_t)(node0 + rr) * FIN + kc + cc];
            xs_t[cc + 0][rr] = v.x;
            xs_t[cc + 1][rr] = v.y;
            xs_t[cc + 2][rr] = v.z;
            xs_t[cc + 3][rr] = v.w;
        }
        __syncthreads();
#pragma unroll 4
        for (int k = 0; k < KC; ++k) {
            float4 a4 = *(const float4*)&xs_t[k][ty * 4];
            float4 b4 = *(const float4*)&Ws[kc + k][tx * 4];
            acc[0][0] = fmaf(a4.x, b4.x, acc[0][0]);
            acc[0][1] = fmaf(a4.x, b4.y, acc[0][1]);
            acc[0][2] = fmaf(a4.x, b4.z, acc[0][2]);
            acc[0][3] = fmaf(a4.x, b4.w, acc[0][3]);
            acc[1][0] = fmaf(a4.y, b4.x, acc[1][0]);
            acc[1][1] = fmaf(a4.y, b4.y, acc[1][1]);
            acc[1][2] = fmaf(a4.y, b4.z, acc[1][2]);
            acc[1][3] = fmaf(a4.y, b4.w, acc[1][3]);
            acc[2][0] = fmaf(a4.z, b4.x, acc[2][0]);
            acc[2][1] = fmaf(a4.z, b4.y, acc[2][1]);
            acc[2][2] = fmaf(a4.z, b4.z, acc[2][2]);
            acc[2][3] = fmaf(a4.z, b4.w, acc[2][3]);
            acc[3][0] = fmaf(a4.w, b4.x, acc[3][0]);
            acc[3][1] = fmaf(a4.w, b4.y, acc[3][1]);
            acc[3][2] = fmaf(a4.w, b4.z, acc[3][2]);
            acc[3][3] = fmaf(a4.w, b4.w, acc[3][3]);
        }
    }

#pragma unroll
    for (int i = 0; i < 4; ++i) {
        int node = node0 + ty * 4 + i;
        if (node < n) {
            float d = dinv[node];
            float4 o = make_float4(acc[i][0] * d, acc[i][1] * d, acc[i][2] * d, acc[i][3] * d);
            *(float4*)&linS[(size_t)node * HH + tx * 4] = o;
        }
    }
}

// ---------------- layer-1 gather: serial 4-deep (R12/R15-verified) ----------------
__global__ void k_gather_w(const float* __restrict__ lin, const int* __restrict__ csr,
                           const int* __restrict__ rowptr, const int* __restrict__ cnt,
                           const float* __restrict__ dinv, const float* __restrict__ b,
                           float* __restrict__ hout, int n) {
    int node = blockIdx.x * (blockDim.x >> 6) + (threadIdx.x >> 6);
    int lane = threadIdx.x & 63;
    if (node >= n) return;
    int start = rowptr[node];
    int end = start + cnt[node];
    float di = dinv[node];
    float acc0 = di * lin[(size_t)node * HH + lane];   // self: dinv[c]*lin[c]
    float acc1 = 0.f, acc2 = 0.f, acc3 = 0.f;
    for (int base = start; base < end; base += 64) {
        int m = end - base; if (m > 64) m = 64;
        int   sv = (base + lane < end) ? csr[base + lane] : 0;
        float wv = (base + lane < end) ? dinv[sv] : 0.f;
        int j = 0;
        for (; j + 3 < m; j += 4) {
            int s0 = __shfl(sv, j, 64);     float w0 = __shfl(wv, j, 64);
            int s1 = __shfl(sv, j + 1, 64); float w1 = __shfl(wv, j + 1, 64);
            int s2 = __shfl(sv, j + 2, 64); float w2 = __shfl(wv, j + 2, 64);
            int s3 = __shfl(sv, j + 3, 64); float w3 = __shfl(wv, j + 3, 64);
            float v0 = lin[(size_t)s0 * HH + lane];
            float v1 = lin[(size_t)s1 * HH + lane];
            float v2 = lin[(size_t)s2 * HH + lane];
            float v3 = lin[(size_t)s3 * HH + lane];
            acc0 = fmaf(w0, v0, acc0);
            acc1 = fmaf(w1, v1, acc1);
            acc2 = fmaf(w2, v2, acc2);
            acc3 = fmaf(w3, v3, acc3);
        }
        for (; j < m; ++j) {
            int s0 = __shfl(sv, j, 64); float w0 = __shfl(wv, j, 64);
            acc0 = fmaf(w0, lin[(size_t)s0 * HH + lane], acc0);
        }
    }
    float v = di * ((acc0 + acc1) + (acc2 + acc3)) + b[lane];
    float ss = v * v;
#pragma unroll
    for (int off = 1; off < 64; off <<= 1) ss += __shfl_xor(ss, off, 64);
    v = v / fmaxf(sqrtf(ss), 1e-12f);
    hout[(size_t)node * HH + lane] = fmaxf(v, 0.f);
}

// ---------------- layers 2-3 gather: quarter-wave float4, FIXED ----------------
// R14's bug: shfl inside a lane-divergent ternary (ds_bpermute reading masked
// lanes = data loss). Fix: ALL shfls unconditional (uniform exec). The m-guard
// lives entirely in wv (=0 for lanes past end); index math proves source lane
// = j + q*4 + t <= 48+12+3 = 63, so no wrap guard is needed either.
__global__ __launch_bounds__(256) void k_gather_q(const float* __restrict__ linS,
                                                  const int* __restrict__ csr,
                                                  const int* __restrict__ rowptr,
                                                  const int* __restrict__ cnt,
                                                  const float* __restrict__ dinv,
                                                  const float* __restrict__ b,
                                                  float* __restrict__ hout, int n) {
    int node = blockIdx.x * 4 + (threadIdx.x >> 6);
    int lane = threadIdx.x & 63;
    if (node >= n) return;
    const int q  = lane >> 4;          // quarter 0..3
    const int fl = (lane & 15) * 4;    // float4 feature offset
    int start = rowptr[node];
    int end = start + cnt[node];
    float di = dinv[node];

    float4 a0 = make_float4(0.f, 0.f, 0.f, 0.f);
    float4 a1 = make_float4(0.f, 0.f, 0.f, 0.f);

    for (int base = start; base < end; base += 64) {
        int m = end - base; if (m > 64) m = 64;
        int idx = base + lane;
        int   sv = (idx < end) ? csr[idx] : 0;
        float wv = (idx < end) ? 1.f : 0.f;
        for (int j = 0; j < m; j += 16) {
            int l = j + q * 4;                       // <= 63 always
            int   s0 = __shfl(sv, l, 64);            // unconditional, uniform
            int   s1 = __shfl(sv, l + 1, 64);
            int   s2 = __shfl(sv, l + 2, 64);
            int   s3 = __shfl(sv, l + 3, 64);
            float w0 = __shfl(wv, l, 64);
            float w1 = __shfl(wv, l + 1, 64);
            float w2 = __shfl(wv, l + 2, 64);
            float w3 = __shfl(wv, l + 3, 64);
            float4 v0 = *(const float4*)&linS[(size_t)s0 * HH + fl];
            float4 v1 = *(const float4*)&linS[(size_t)s1 * HH + fl];
            float4 v2 = *(const float4*)&linS[(size_t)s2 * HH + fl];
            float4 v3 = *(const float4*)&linS[(size_t)s3 * HH + fl];
            a0.x = fmaf(w0, v0.x, a0.x); a0.y = fmaf(w0, v0.y, a0.y);
            a0.z = fmaf(w0, v0.z, a0.z); a0.w = fmaf(w0, v0.w, a0.w);
            a1.x = fmaf(w1, v1.x, a1.x); a1.y = fmaf(w1, v1.y, a1.y);
            a1.z = fmaf(w1, v1.z, a1.z); a1.w = fmaf(w1, v1.w, a1.w);
            a0.x = fmaf(w2, v2.x, a0.x); a0.y = fmaf(w2, v2.y, a0.y);
            a0.z = fmaf(w2, v2.z, a0.z); a0.w = fmaf(w2, v2.w, a0.w);
            a1.x = fmaf(w3, v3.x, a1.x); a1.y = fmaf(w3, v3.y, a1.y);
            a1.z = fmaf(w3, v3.z, a1.z); a1.w = fmaf(w3, v3.w, a1.w);
        }
    }
    float4 acc = make_float4(a0.x + a1.x, a0.y + a1.y, a0.z + a1.z, a0.w + a1.w);
    // combine quarters (lane&15 preserved under xor 16/32); unconditional shfls
#pragma unroll
    for (int off = 16; off < 64; off <<= 1) {
        acc.x += __shfl_xor(acc.x, off, 64);
        acc.y += __shfl_xor(acc.y, off, 64);
        acc.z += __shfl_xor(acc.z, off, 64);
        acc.w += __shfl_xor(acc.w, off, 64);
    }
    // self-loop term (carries one dinv factor already)
    float4 self = *(const float4*)&linS[(size_t)node * HH + fl];
    acc.x += self.x; acc.y += self.y; acc.z += self.z; acc.w += self.w;
    // bias + L2 norm + relu
    float4 b4 = *(const float4*)&b[fl];
    float4 v4 = make_float4(fmaf(di, acc.x, b4.x), fmaf(di, acc.y, b4.y),
                            fmaf(di, acc.z, b4.z), fmaf(di, acc.w, b4.w));
    float ss = v4.x * v4.x + v4.y * v4.y + v4.z * v4.z + v4.w * v4.w;
#pragma unroll
    for (int off = 1; off < 16; off <<= 1) ss += __shfl_xor(ss, off, 64);
    float inv = 1.f / fmaxf(sqrtf(ss), 1e-12f);
    v4.x = fmaxf(v4.x * inv, 0.f);
    v4.y = fmaxf(v4.y * inv, 0.f);
    v4.z = fmaxf(v4.z * inv, 0.f);
    v4.w = fmaxf(v4.w * inv, 0.f);
    if (q == 0) *(float4*)&hout[(size_t)node * HH + fl] = v4;
}

// ---------------- pooling ----------------
__global__ __launch_bounds__(256) void k_pool(const float* __restrict__ node_emb,
                                              const int* __restrict__ batch,
                                              float* __restrict__ sums,
                                              float* __restrict__ cnts, int n) {
    const int NPW = 16;
    int wave = blockIdx.x * 4 + (threadIdx.x >> 6);
    int lane = threadIdx.x & 63;
    int start = wave * NPW;
    if (start >= n) return;
    int end = start + NPW; if (end > n) end = n;
    int cur = batch[start];
    float acc = 0.f;
    int runlen = 0;
    for (int node = start; node < end; ++node) {
        int g = batch[node];
        if (g != cur) {
            atomicAdd(&sums[(size_t)cur * HH + lane], acc);
            if (lane == 0) atomicAdd(&cnts[cur], (float)runlen);
            acc = 0.f; runlen = 0; cur = g;
        }
        acc += node_emb[(size_t)node * HH + lane];
        ++runlen;
    }
    atomicAdd(&sums[(size_t)cur * HH + lane], acc);
    if (lane == 0) atomicAdd(&cnts[cur], (float)runlen);
}

// ---------------- classifier + softmax ----------------
__global__ void k_final2(const float* __restrict__ sums, const float* __restrict__ cnts,
                         const float* __restrict__ Wm, const float* __restrict__ bm,
                         float* __restrict__ logits, float* __restrict__ probs,
                         float* __restrict__ graph_emb) {
    int g = blockIdx.x;
    int lane = threadIdx.x;
    float mean = sums[(size_t)g * HH + lane] / fmaxf(cnts[g], 1.0f);
    graph_emb[(size_t)g * HH + lane] = mean;

    __shared__ float semb[HH];
    __shared__ float slog[16];
    semb[lane] = mean;
    __syncthreads();
    if (lane < 10) {
        float acc = bm[lane];
        for (int k = 0; k < HH; ++k) acc = fmaf(semb[k], Wm[k * 10 + lane], acc);
        slog[lane] = acc;
    }
    __syncthreads();
    if (lane < 10) {
        float mx = -1e30f;
        for (int j = 0; j < 10; ++j) mx = fmaxf(mx, slog[j]);
        float den = 0.f;
        for (int j = 0; j < 10; ++j) den += __expf(slog[j] - mx);
        float lg = slog[lane];
        logits[g * 10 + lane] = lg;
        probs[g * 10 + lane] = __expf(lg - mx) / den;
    }
}

// ---------------- launch ----------------

extern "C" void kernel_launch(void* const* d_in, const int* in_sizes, int n_in,
                              void* d_out, int out_size, void* d_ws, size_t ws_size,
                              hipStream_t stream) {
    const float* x     = (const float*)d_in[0];
    const int*   ei    = (const int*)  d_in[1];
    const int*   batch = (const int*)  d_in[2];
    const float* W1 = (const float*)d_in[3];  const float* b1 = (const float*)d_in[4];
    const float* W2 = (const float*)d_in[5];  const float* b2 = (const float*)d_in[6];
    const float* W3 = (const float*)d_in[7];  const float* b3 = (const float*)d_in[8];
    const float* Wm = (const float*)d_in[9];  const float* bm = (const float*)d_in[10];

    const int N = in_sizes[2];
    const int E = in_sizes[1] / 2;
    const int G = (out_size - N * HH) / (2 * 10 + HH);

    const int* row = ei;
    const int* col = ei + E;

    float* out       = (float*)d_out;
    float* logits    = out;
    float* probs     = out + (size_t)G * 10;
    float* node_emb  = out + (size_t)2 * G * 10;
    float* graph_emb = node_emb + (size_t)N * HH;

    char* w = (char*)d_ws;
    auto alloc = [&](size_t bytes) { char* p = w; w += (bytes + 255) & ~(size_t)255; return p; };
    float* dinv    = (float*)alloc((size_t)N * 4);
    int*   cnt     = (int*)  alloc((size_t)N * 4);
    int*   rowptr  = (int*)  alloc((size_t)N * 4);
    int*   head    = (int*)  alloc((size_t)N * 4);
    int*   nxt     = (int*)  alloc((size_t)E * 4);
    int*   cursor  = (int*)  alloc(256);
    float* sums    = (float*)alloc((size_t)G * HH * 4 + (size_t)G * 4);
    float* cnts    = sums + (size_t)G * HH;
    int*   csr     = (int*)  alloc((size_t)E * 4);
    float* bufA    = (float*)alloc((size_t)N * HH * 4);
    float* bufB    = (float*)alloc((size_t)N * HH * 4);

    const int B = 256;
    dim3 blk(B);
    int node_blocks = (N + 3) / 4;
    int gemm_blocks = (N + 63) / 64;
    int nB = (N + B - 1) / B;
    int eB = (E + B - 1) / B;
    int poolN = G * HH + G;
    int pool_blocks = (N + 63) / 64;

    // CSR build: init -> pure link -> fused(walk + layer-1 gemm) [R15 structure]
    k_init<<<nB, blk, 0, stream>>>(head, sums, cursor, N, poolN);
    k_link<<<eB, blk, 0, stream>>>(col, E, head, nxt);
    k_walk_gemm<128><<<gemm_blocks, blk, 0, stream>>>(row, head, nxt, cursor, rowptr, cnt,
                                                      dinv, csr, x, W1, bufA, N);

    // layer 1: weighted serial gather (bufA -> bufB = h1)
    k_gather_w<<<node_blocks, blk, 0, stream>>>(bufA, csr, rowptr, cnt, dinv, b1, bufB, N);
    // layer 2: prescaled gemm + quarter-wave gather (bufB -> bufA -> bufB = h2)
    k_gemm2<64><<<gemm_blocks, blk, 0, stream>>>(bufB, W2, dinv, bufA, N);
    k_gather_q<<<node_blocks, blk, 0, stream>>>(bufA, csr, rowptr, cnt, dinv, b2, bufB, N);
    // layer 3: prescaled gemm + quarter-wave gather (bufB -> bufA -> node_emb)
    k_gemm2<64><<<gemm_blocks, blk, 0, stream>>>(bufB, W3, dinv, bufA, N);
    k_gather_q<<<node_blocks, blk, 0, stream>>>(bufA, csr, rowptr, cnt, dinv, b3, node_emb, N);

    // pool + classifier
    k_pool<<<pool_blocks, blk, 0, stream>>>(node_emb, batch, sums, cnts, N);
    k_final2<<<G, dim3(64), 0, stream>>>(sums, cnts, Wm, bm, logits, probs, graph_emb);
}

// Round 18
// 306.222 us; speedup vs baseline: 1.0946x; 1.0158x over previous
//
#include <hip/hip_runtime.h>
#include <math.h>

#define HH 64

// ---------------- init ----------------

__global__ void k_init(int* __restrict__ head, float* __restrict__ sums,
                       int* __restrict__ cursor, int n, int pn) {
    int i = blockIdx.x * blockDim.x + threadIdx.x;
    if (i < n) head[i] = -1;
    if (i < pn) sums[i] = 0.f;
    if (i == 0) *cursor = 0;
}

// ---------------- CSR build: pure linked-list pass ----------------
__global__ void k_link(const int* __restrict__ col, int E,
                       int* __restrict__ head, int* __restrict__ next) {
    int e = blockIdx.x * blockDim.x + threadIdx.x;
    if (e >= E) return;
    int c = col[e];
    int prev = atomicExch(&head[c], e);
    next[e] = prev;
}

// ---------------- fused: list-walk/CSR-alloc + layer-1 GEMM (R15/R17-verified) ----------------
template<int FIN>
__global__ __launch_bounds__(256, 3) void k_walk_gemm(const int* __restrict__ row,
                                                      const int* __restrict__ head,
                                                      const int* __restrict__ next,
                                                      int* __restrict__ cursor,
                                                      int* __restrict__ rowptr,
                                                      int* __restrict__ cnt,
                                                      float* __restrict__ dinv,
                                                      int* __restrict__ csr,
                                                      const float* __restrict__ x,
                                                      const float* __restrict__ W,
                                                      float* __restrict__ lin, int n) {
    constexpr int KC = 32;
    constexpr int XS = 68;
    __shared__ __align__(16) float Ws[FIN][HH];
    __shared__ __align__(16) float xs_t[KC][XS];
    const int tid = threadIdx.x;

    // ---- walk + alloc ----
    {
        int node = blockIdx.x * 256 + tid;
        int lane = tid & 63;
        if (node - tid < n) {
            int len = 0, h = -1;
            if (node < n) {
                h = head[node];
                for (int p = h; p >= 0; p = next[p]) ++len;
                dinv[node] = rsqrtf((float)(len + 1));
            }
            int incl = len;
#pragma unroll
            for (int off = 1; off < 64; off <<= 1) {
                int t = __shfl_up(incl, off, 64);
                if (lane >= off) incl += t;
            }
            int total = __shfl(incl, 63, 64);
            int base = 0;
            if (lane == 0 && total > 0) base = atomicAdd(cursor, total);
            base = __shfl(base, 0, 64);
            int dst = base + incl - len;
            if (node < n) {
                rowptr[node] = dst;
                cnt[node]    = len;
                for (int p = h; p >= 0; p = next[p]) csr[dst++] = row[p];
            }
        }
    }

    // ---- layer-1 gemm (unscaled output) ----
    const int tx = tid & 15;
    const int ty = tid >> 4;
    const int node0 = blockIdx.x * 64;
    if (node0 >= n) return;

    for (int i = tid * 4; i < FIN * HH; i += 1024)
        *(float4*)&Ws[0][i] = *(const float4*)&W[i];

    float acc[4][4] = {};
    const int rr0 = tid >> 3;
    const int cc  = (tid & 7) * 4;

    for (int kc = 0; kc < FIN; kc += KC) {
        __syncthreads();
        for (int rr = rr0; rr < 64; rr += 32) {
            float4 v = make_float4(0.f, 0.f, 0.f, 0.f);
            if (node0 + rr < n) v = *(const float4*)&x[(size_t)(node0 + rr) * FIN + kc + cc];
            xs_t[cc + 0][rr] = v.x;
            xs_t[cc + 1][rr] = v.y;
            xs_t[cc + 2][rr] = v.z;
            xs_t[cc + 3][rr] = v.w;
        }
        __syncthreads();
#pragma unroll 4
        for (int k = 0; k < KC; ++k) {
            float4 a4 = *(const float4*)&xs_t[k][ty * 4];
            float4 b4 = *(const float4*)&Ws[kc + k][tx * 4];
            acc[0][0] = fmaf(a4.x, b4.x, acc[0][0]);
            acc[0][1] = fmaf(a4.x, b4.y, acc[0][1]);
            acc[0][2] = fmaf(a4.x, b4.z, acc[0][2]);
            acc[0][3] = fmaf(a4.x, b4.w, acc[0][3]);
            acc[1][0] = fmaf(a4.y, b4.x, acc[1][0]);
            acc[1][1] = fmaf(a4.y, b4.y, acc[1][1]);
            acc[1][2] = fmaf(a4.y, b4.z, acc[1][2]);
            acc[1][3] = fmaf(a4.y, b4.w, acc[1][3]);
            acc[2][0] = fmaf(a4.z, b4.x, acc[2][0]);
            acc[2][1] = fmaf(a4.z, b4.y, acc[2][1]);
            acc[2][2] = fmaf(a4.z, b4.z, acc[2][2]);
            acc[2][3] = fmaf(a4.z, b4.w, acc[2][3]);
            acc[3][0] = fmaf(a4.w, b4.x, acc[3][0]);
            acc[3][1] = fmaf(a4.w, b4.y, acc[3][1]);
            acc[3][2] = fmaf(a4.w, b4.z, acc[3][2]);
            acc[3][3] = fmaf(a4.w, b4.w, acc[3][3]);
        }
    }

#pragma unroll
    for (int i = 0; i < 4; ++i) {
        int node = node0 + ty * 4 + i;
        if (node < n) *(float4*)&lin[(size_t)node * HH + tx * 4] = *(float4*)acc[i];
    }
}

// ---------------- dense transform (layers 2-3): pre-scaled by dinv ----------------
template<int FIN>
__global__ __launch_bounds__(256, 4) void k_gemm2(const float* __restrict__ x,
                                                  const float* __restrict__ W,
                                                  const float* __restrict__ dinv,
                                                  float* __restrict__ linS, int n) {
    constexpr int KC = 32;
    constexpr int XS = 68;
    __shared__ __align__(16) float Ws[FIN][HH];
    __shared__ __align__(16) float xs_t[KC][XS];
    const int tid = threadIdx.x;
    const int tx = tid & 15;
    const int ty = tid >> 4;
    const int node0 = blockIdx.x * 64;

    for (int i = tid * 4; i < FIN * HH; i += 1024)
        *(float4*)&Ws[0][i] = *(const float4*)&W[i];

    float acc[4][4] = {};
    const int rr0 = tid >> 3;
    const int cc  = (tid & 7) * 4;

    for (int kc = 0; kc < FIN; kc += KC) {
        __syncthreads();
        for (int rr = rr0; rr < 64; rr += 32) {
            float4 v = make_float4(0.f, 0.f, 0.f, 0.f);
            if (node0 + rr < n) v = *(const float4*)&x[(size_t)(node0 + rr) * FIN + kc + cc];
            xs_t[cc + 0][rr] = v.x;
            xs_t[cc + 1][rr] = v.y;
            xs_t[cc + 2][rr] = v.z;
            xs_t[cc + 3][rr] = v.w;
        }
        __syncthreads();
#pragma unroll 4
        for (int k = 0; k < KC; ++k) {
            float4 a4 = *(const float4*)&xs_t[k][ty * 4];
            float4 b4 = *(const float4*)&Ws[kc + k][tx * 4];
            acc[0][0] = fmaf(a4.x, b4.x, acc[0][0]);
            acc[0][1] = fmaf(a4.x, b4.y, acc[0][1]);
            acc[0][2] = fmaf(a4.x, b4.z, acc[0][2]);
            acc[0][3] = fmaf(a4.x, b4.w, acc[0][3]);
            acc[1][0] = fmaf(a4.y, b4.x, acc[1][0]);
            acc[1][1] = fmaf(a4.y, b4.y, acc[1][1]);
            acc[1][2] = fmaf(a4.y, b4.z, acc[1][2]);
            acc[1][3] = fmaf(a4.y, b4.w, acc[1][3]);
            acc[2][0] = fmaf(a4.z, b4.x, acc[2][0]);
            acc[2][1] = fmaf(a4.z, b4.y, acc[2][1]);
            acc[2][2] = fmaf(a4.z, b4.z, acc[2][2]);
            acc[2][3] = fmaf(a4.z, b4.w, acc[2][3]);
            acc[3][0] = fmaf(a4.w, b4.x, acc[3][0]);
            acc[3][1] = fmaf(a4.w, b4.y, acc[3][1]);
            acc[3][2] = fmaf(a4.w, b4.z, acc[3][2]);
            acc[3][3] = fmaf(a4.w, b4.w, acc[3][3]);
        }
    }

#pragma unroll
    for (int i = 0; i < 4; ++i) {
        int node = node0 + ty * 4 + i;
        if (node < n) {
            float d = dinv[node];
            float4 o = make_float4(acc[i][0] * d, acc[i][1] * d, acc[i][2] * d, acc[i][3] * d);
            *(float4*)&linS[(size_t)node * HH + tx * 4] = o;
        }
    }
}

// ---------------- gather: quarter-wave float4 (R17-verified structure) ----------------
// WEIGHTED (layer 1): lin unscaled, per-edge weight dinv[src], self weight di.
// else (layers 2-3): linS pre-scaled, weight 1, self weight 1.
// All cross-lane shfls UNCONDITIONAL (uniform exec — the R14 lesson); range
// guards live in wv only. Source lane j+q*4+t <= 63, no wrap needed.
template<bool WEIGHTED>
__global__ __launch_bounds__(256) void k_gather_q(const float* __restrict__ lin,
                                                  const int* __restrict__ csr,
                                                  const int* __restrict__ rowptr,
                                                  const int* __restrict__ cnt,
                                                  const float* __restrict__ dinv,
                                                  const float* __restrict__ b,
                                                  float* __restrict__ hout, int n) {
    int node = blockIdx.x * 4 + (threadIdx.x >> 6);
    int lane = threadIdx.x & 63;
    if (node >= n) return;
    const int q  = lane >> 4;          // quarter 0..3
    const int fl = (lane & 15) * 4;    // float4 feature offset
    int start = rowptr[node];
    int end = start + cnt[node];
    float di = dinv[node];

    float4 a0 = make_float4(0.f, 0.f, 0.f, 0.f);
    float4 a1 = make_float4(0.f, 0.f, 0.f, 0.f);

    for (int base = start; base < end; base += 64) {
        int m = end - base; if (m > 64) m = 64;
        int idx = base + lane;
        int   sv = (idx < end) ? csr[idx] : 0;
        float wv;
        if (WEIGHTED) wv = (idx < end) ? dinv[sv] : 0.f;   // predicated load: safe
        else          wv = (idx < end) ? 1.f : 0.f;
        for (int j = 0; j < m; j += 16) {
            int l = j + q * 4;                       // <= 63 always
            int   s0 = __shfl(sv, l, 64);            // unconditional, uniform
            int   s1 = __shfl(sv, l + 1, 64);
            int   s2 = __shfl(sv, l + 2, 64);
            int   s3 = __shfl(sv, l + 3, 64);
            float w0 = __shfl(wv, l, 64);
            float w1 = __shfl(wv, l + 1, 64);
            float w2 = __shfl(wv, l + 2, 64);
            float w3 = __shfl(wv, l + 3, 64);
            float4 v0 = *(const float4*)&lin[(size_t)s0 * HH + fl];
            float4 v1 = *(const float4*)&lin[(size_t)s1 * HH + fl];
            float4 v2 = *(const float4*)&lin[(size_t)s2 * HH + fl];
            float4 v3 = *(const float4*)&lin[(size_t)s3 * HH + fl];
            a0.x = fmaf(w0, v0.x, a0.x); a0.y = fmaf(w0, v0.y, a0.y);
            a0.z = fmaf(w0, v0.z, a0.z); a0.w = fmaf(w0, v0.w, a0.w);
            a1.x = fmaf(w1, v1.x, a1.x); a1.y = fmaf(w1, v1.y, a1.y);
            a1.z = fmaf(w1, v1.z, a1.z); a1.w = fmaf(w1, v1.w, a1.w);
            a0.x = fmaf(w2, v2.x, a0.x); a0.y = fmaf(w2, v2.y, a0.y);
            a0.z = fmaf(w2, v2.z, a0.z); a0.w = fmaf(w2, v2.w, a0.w);
            a1.x = fmaf(w3, v3.x, a1.x); a1.y = fmaf(w3, v3.y, a1.y);
            a1.z = fmaf(w3, v3.z, a1.z); a1.w = fmaf(w3, v3.w, a1.w);
        }
    }
    float4 acc = make_float4(a0.x + a1.x, a0.y + a1.y, a0.z + a1.z, a0.w + a1.w);
#pragma unroll
    for (int off = 16; off < 64; off <<= 1) {
        acc.x += __shfl_xor(acc.x, off, 64);
        acc.y += __shfl_xor(acc.y, off, 64);
        acc.z += __shfl_xor(acc.z, off, 64);
        acc.w += __shfl_xor(acc.w, off, 64);
    }
    // self-loop term: weight di (weighted) or 1 (pre-scaled input)
    float4 self = *(const float4*)&lin[(size_t)node * HH + fl];
    float sw = WEIGHTED ? di : 1.f;
    acc.x = fmaf(sw, self.x, acc.x);
    acc.y = fmaf(sw, self.y, acc.y);
    acc.z = fmaf(sw, self.z, acc.z);
    acc.w = fmaf(sw, self.w, acc.w);
    // bias + L2 norm + relu
    float4 b4 = *(const float4*)&b[fl];
    float4 v4 = make_float4(fmaf(di, acc.x, b4.x), fmaf(di, acc.y, b4.y),
                            fmaf(di, acc.z, b4.z), fmaf(di, acc.w, b4.w));
    float ss = v4.x * v4.x + v4.y * v4.y + v4.z * v4.z + v4.w * v4.w;
#pragma unroll
    for (int off = 1; off < 16; off <<= 1) ss += __shfl_xor(ss, off, 64);
    float inv = 1.f / fmaxf(sqrtf(ss), 1e-12f);
    v4.x = fmaxf(v4.x * inv, 0.f);
    v4.y = fmaxf(v4.y * inv, 0.f);
    v4.z = fmaxf(v4.z * inv, 0.f);
    v4.w = fmaxf(v4.w * inv, 0.f);
    if (q == 0) *(float4*)&hout[(size_t)node * HH + fl] = v4;
}

// ---------------- pooling ----------------
__global__ __launch_bounds__(256) void k_pool(const float* __restrict__ node_emb,
                                              const int* __restrict__ batch,
                                              float* __restrict__ sums,
                                              float* __restrict__ cnts, int n) {
    const int NPW = 16;
    int wave = blockIdx.x * 4 + (threadIdx.x >> 6);
    int lane = threadIdx.x & 63;
    int start = wave * NPW;
    if (start >= n) return;
    int end = start + NPW; if (end > n) end = n;
    int cur = batch[start];
    float acc = 0.f;
    int runlen = 0;
    for (int node = start; node < end; ++node) {
        int g = batch[node];
        if (g != cur) {
            atomicAdd(&sums[(size_t)cur * HH + lane], acc);
            if (lane == 0) atomicAdd(&cnts[cur], (float)runlen);
            acc = 0.f; runlen = 0; cur = g;
        }
        acc += node_emb[(size_t)node * HH + lane];
        ++runlen;
    }
    atomicAdd(&sums[(size_t)cur * HH + lane], acc);
    if (lane == 0) atomicAdd(&cnts[cur], (float)runlen);
}

// ---------------- classifier + softmax ----------------
__global__ void k_final2(const float* __restrict__ sums, const float* __restrict__ cnts,
                         const float* __restrict__ Wm, const float* __restrict__ bm,
                         float* __restrict__ logits, float* __restrict__ probs,
                         float* __restrict__ graph_emb) {
    int g = blockIdx.x;
    int lane = threadIdx.x;
    float mean = sums[(size_t)g * HH + lane] / fmaxf(cnts[g], 1.0f);
    graph_emb[(size_t)g * HH + lane] = mean;

    __shared__ float semb[HH];
    __shared__ float slog[16];
    semb[lane] = mean;
    __syncthreads();
    if (lane < 10) {
        float acc = bm[lane];
        for (int k = 0; k < HH; ++k) acc = fmaf(semb[k], Wm[k * 10 + lane], acc);
        slog[lane] = acc;
    }
    __syncthreads();
    if (lane < 10) {
        float mx = -1e30f;
        for (int j = 0; j < 10; ++j) mx = fmaxf(mx, slog[j]);
        float den = 0.f;
        for (int j = 0; j < 10; ++j) den += __expf(slog[j] - mx);
        float lg = slog[lane];
        logits[g * 10 + lane] = lg;
        probs[g * 10 + lane] = __expf(lg - mx) / den;
    }
}

// ---------------- launch ----------------

extern "C" void kernel_launch(void* const* d_in, const int* in_sizes, int n_in,
                              void* d_out, int out_size, void* d_ws, size_t ws_size,
                              hipStream_t stream) {
    const float* x     = (const float*)d_in[0];
    const int*   ei    = (const int*)  d_in[1];
    const int*   batch = (const int*)  d_in[2];
    const float* W1 = (const float*)d_in[3];  const float* b1 = (const float*)d_in[4];
    const float* W2 = (const float*)d_in[5];  const float* b2 = (const float*)d_in[6];
    const float* W3 = (const float*)d_in[7];  const float* b3 = (const float*)d_in[8];
    const float* Wm = (const float*)d_in[9];  const float* bm = (const float*)d_in[10];

    const int N = in_sizes[2];
    const int E = in_sizes[1] / 2;
    const int G = (out_size - N * HH) / (2 * 10 + HH);

    const int* row = ei;
    const int* col = ei + E;

    float* out       = (float*)d_out;
    float* logits    = out;
    float* probs     = out + (size_t)G * 10;
    float* node_emb  = out + (size_t)2 * G * 10;
    float* graph_emb = node_emb + (size_t)N * HH;

    char* w = (char*)d_ws;
    auto alloc = [&](size_t bytes) { char* p = w; w += (bytes + 255) & ~(size_t)255; return p; };
    float* dinv    = (float*)alloc((size_t)N * 4);
    int*   cnt     = (int*)  alloc((size_t)N * 4);
    int*   rowptr  = (int*)  alloc((size_t)N * 4);
    int*   head    = (int*)  alloc((size_t)N * 4);
    int*   nxt     = (int*)  alloc((size_t)E * 4);
    int*   cursor  = (int*)  alloc(256);
    float* sums    = (float*)alloc((size_t)G * HH * 4 + (size_t)G * 4);
    float* cnts    = sums + (size_t)G * HH;
    int*   csr     = (int*)  alloc((size_t)E * 4);
    float* bufA    = (float*)alloc((size_t)N * HH * 4);
    float* bufB    = (float*)alloc((size_t)N * HH * 4);

    const int B = 256;
    dim3 blk(B);
    int node_blocks = (N + 3) / 4;
    int gemm_blocks = (N + 63) / 64;
    int nB = (N + B - 1) / B;
    int eB = (E + B - 1) / B;
    int poolN = G * HH + G;
    int pool_blocks = (N + 63) / 64;

    // CSR build: init -> pure link -> fused(walk + layer-1 gemm)
    k_init<<<nB, blk, 0, stream>>>(head, sums, cursor, N, poolN);
    k_link<<<eB, blk, 0, stream>>>(col, E, head, nxt);
    k_walk_gemm<128><<<gemm_blocks, blk, 0, stream>>>(row, head, nxt, cursor, rowptr, cnt,
                                                      dinv, csr, x, W1, bufA, N);

    // layer 1: weighted quarter-wave gather (bufA -> bufB = h1)
    k_gather_q<true><<<node_blocks, blk, 0, stream>>>(bufA, csr, rowptr, cnt, dinv, b1, bufB, N);
    // layer 2: prescaled gemm + quarter-wave gather (bufB -> bufA -> bufB = h2)
    k_gemm2<64><<<gemm_blocks, blk, 0, stream>>>(bufB, W2, dinv, bufA, N);
    k_gather_q<false><<<node_blocks, blk, 0, stream>>>(bufA, csr, rowptr, cnt, dinv, b2, bufB, N);
    // layer 3: prescaled gemm + quarter-wave gather (bufB -> bufA -> node_emb)
    k_gemm2<64><<<gemm_blocks, blk, 0, stream>>>(bufB, W3, dinv, bufA, N);
    k_gather_q<false><<<node_blocks, blk, 0, stream>>>(bufA, csr, rowptr, cnt, dinv, b3, node_emb, N);

    // pool + classifier
    k_pool<<<pool_blocks, blk, 0, stream>>>(node_emb, batch, sums, cnts, N);
    k_final2<<<G, dim3(64), 0, stream>>>(sums, cnts, Wm, bm, logits, probs, graph_emb);
}